// Round 11
// baseline (6606.747 us; speedup 1.0000x reference)
//
#include <hip/hip_runtime.h>
#include <hip/hip_fp16.h>

typedef unsigned long long u64;

#define SEG_N     8192
#define NSEG      2
#define M_PER_SEG 2048
#define M_TOTAL   4096
#define CFEAT     64
#define COUT      128
#define NSAMPLE   16

#define FPS_WGS_PER_SEG 16
#define FPS_THREADS     512
#define FPS_WAVES       8
#define SLOT_STRIDE     16    // u64s per (parity,seg) row = 128B line

// d_out layout (floats): new_xyz | new_feat | new_offset | new_vel
#define OUT_XYZ   0
#define OUT_FEAT  12288      // 4096*3
#define OUT_OFF   536576     // + 4096*128
#define OUT_VEL   536578     // + 2

// d_ws layout (bytes)
#define WS_CAND 0            // u64 cand[2][2][16]  (fallback sync slots)
#define WS_FPS  512          // int fps_idx[2][2048]
#define WS_KNN  16896        // int knn[4096][16]
#define WS_SQ   (1<<19)      // float sq[16384]
#define WS_D2   (1<<20)      // u16 D2 matrix region
#define D2_SEG  ((size_t)SEG_N * SEG_N * 2)   // 134 MB per segment
#define D2_SCALE 128.0f

#define AG  __HIP_MEMORY_SCOPE_AGENT
#define RLX __ATOMIC_RELAXED

#define REP16(M) M(0) M(1) M(2) M(3) M(4) M(5) M(6) M(7) \
                 M(8) M(9) M(10) M(11) M(12) M(13) M(14) M(15)
#define REP16_EO(E,O) E(0) O(1) E(2) O(3) E(4) O(5) E(6) O(7) \
                      E(8) O(9) E(10) O(11) E(12) O(13) E(14) O(15)

__device__ __forceinline__ unsigned pk2(float a, float b) {
  __half2 h = __floats2half2_rn(a, b);
  unsigned u; __builtin_memcpy(&u, &h, 4); return u;
}
__device__ __forceinline__ float2 up2(unsigned u) {
  __half2 h; __builtin_memcpy(&h, &u, 4);
  return __half22float2(h);
}

// ===========================================================================
// FAST PATH: precomputed u16 d^2 matrix (x128 fixed point), per segment.
// Tier A (ws >= 1MB + 268MB): both segments resident, fps WGs run in parallel.
// Tier B (ws >= 1MB + 134MB): sequential gram0->fps0->gram1->fps1 (stream-
// ordered, same buffer reused; one 134MB matrix fits the 256MB L3).
// ===========================================================================

__global__ __launch_bounds__(256)
void norm_kernel(const float* __restrict__ xyz, const float* __restrict__ feat,
                 float* __restrict__ sq)
{
  int i = blockIdx.x * 256 + threadIdx.x;
  if (i >= NSEG * SEG_N) return;
  float a0 = xyz[(size_t)i*3+0], a1 = xyz[(size_t)i*3+1], a2 = xyz[(size_t)i*3+2];
  float acc = a0*a0 + a1*a1 + a2*a2;
  const float4* fr = (const float4*)(feat + (size_t)i * CFEAT);
  #pragma unroll
  for (int k = 0; k < 16; ++k) {
    float4 v = fr[k];
    acc += v.x*v.x + v.y*v.y + v.z*v.z + v.w*v.w;
  }
  sq[i] = acc;
}

// rank-67 GEMM -> u16 d^2 tile (128q x 64p per block), one segment.
__global__ __launch_bounds__(256)
void gram_kernel(const float* __restrict__ xyz, const float* __restrict__ feat,
                 const float* __restrict__ sq, unsigned short* __restrict__ d2seg,
                 int s)
{
  __shared__ float Aq[68][132];
  __shared__ float Ap[68][68];

  const int b   = blockIdx.x;
  const int tq  = b >> 7;               // 0..63
  const int tp  = b & 127;              // 0..127
  const int q0  = tq * 128, p0 = tp * 64;
  const int tid = threadIdx.x;

  for (int e = tid; e < 128 * 64; e += 256) {
    int r = e >> 6, c = e & 63;
    Aq[3 + c][r] = feat[(size_t)(s * SEG_N + q0 + r) * CFEAT + c];
  }
  for (int e = tid; e < 128 * 3; e += 256) {
    int r = e / 3, d = e - r * 3;
    Aq[d][r] = xyz[(size_t)(s * SEG_N + q0 + r) * 3 + d];
  }
  for (int e = tid; e < 64 * 64; e += 256) {
    int r = e >> 6, c = e & 63;
    Ap[3 + c][r] = feat[(size_t)(s * SEG_N + p0 + r) * CFEAT + c];
  }
  for (int e = tid; e < 64 * 3; e += 256) {
    int r = e / 3, d = e - r * 3;
    Ap[d][r] = xyz[(size_t)(s * SEG_N + p0 + r) * 3 + d];
  }
  __syncthreads();

  const int ty = tid >> 4, tx = tid & 15;   // 8q x 4p per thread
  float acc[8][4];
  #pragma unroll
  for (int i = 0; i < 8; ++i)
    #pragma unroll
    for (int j = 0; j < 4; ++j) acc[i][j] = 0.f;

  for (int k = 0; k < 67; ++k) {
    const float* aq = &Aq[k][ty * 8];
    const float* bp = &Ap[k][tx * 4];
    float a[8], bb[4];
    #pragma unroll
    for (int i = 0; i < 8; ++i) a[i] = aq[i];
    #pragma unroll
    for (int j = 0; j < 4; ++j) bb[j] = bp[j];
    #pragma unroll
    for (int i = 0; i < 8; ++i)
      #pragma unroll
      for (int j = 0; j < 4; ++j) acc[i][j] += a[i] * bb[j];
  }

  float sp[4];
  #pragma unroll
  for (int j = 0; j < 4; ++j) sp[j] = sq[s * SEG_N + p0 + tx * 4 + j];

  #pragma unroll
  for (int i = 0; i < 8; ++i) {
    int qrow = q0 + ty * 8 + i;
    float sqq = sq[s * SEG_N + qrow];
    unsigned o[4];
    #pragma unroll
    for (int j = 0; j < 4; ++j) {
      float d2 = sqq + sp[j] - 2.f * acc[i][j];
      d2 = fmaxf(d2, 0.f);
      o[j] = __float2uint_rn(fminf(d2 * D2_SCALE, 65535.f));
    }
    uint2 st; st.x = o[0] | (o[1] << 16); st.y = o[2] | (o[3] << 16);
    *(uint2*)&d2seg[((size_t)qrow << 13) + (p0 + tx * 4)] = st;
  }
}

// FPS from the matrix: ONE workgroup per segment, zero cross-WG sync.
// 1024 threads x 8 points. Per step: one 16B row-slice load, 8 fmin,
// argmax (in-thread -> 64-lane butterfly -> 16-wave LDS funnel), broadcast.
__global__ __launch_bounds__(1024)
void fps_fast_kernel(const unsigned short* __restrict__ d2m, int s0,
                     size_t seg_stride, int* __restrict__ fps_idx)
{
  __shared__ u64 wslot[16];
  __shared__ int qidx_sh;

  const int tid  = threadIdx.x;
  const int lane = tid & 63;
  const int wv   = tid >> 6;
  const int s    = s0 + blockIdx.x;
  const int p0   = tid * 8;
  const unsigned short* base_s = d2m + (size_t)blockIdx.x * seg_stride;

  float D[8];
  #pragma unroll
  for (int k = 0; k < 8; ++k) D[k] = 1e10f;

  if (tid == 0) fps_idx[s * M_PER_SEG] = 0;
  int q = 0;

  for (int t = 1; t < M_PER_SEG; ++t) {
    uint4 w = *(const uint4*)(base_s + ((size_t)q << 13) + p0);
    D[0] = fminf(D[0], (float)(w.x & 0xFFFFu));
    D[1] = fminf(D[1], (float)(w.x >> 16));
    D[2] = fminf(D[2], (float)(w.y & 0xFFFFu));
    D[3] = fminf(D[3], (float)(w.y >> 16));
    D[4] = fminf(D[4], (float)(w.z & 0xFFFFu));
    D[5] = fminf(D[5], (float)(w.z >> 16));
    D[6] = fminf(D[6], (float)(w.w & 0xFFFFu));
    D[7] = fminf(D[7], (float)(w.w >> 16));

    float bd = D[0]; int bk = 0;
    #pragma unroll
    for (int k = 1; k < 8; ++k) if (D[k] > bd) { bd = D[k]; bk = k; }
    int bi = p0 + bk;

    #pragma unroll
    for (int off = 32; off >= 1; off >>= 1) {
      float od = __shfl_xor(bd, off);
      int   oi = __shfl_xor(bi, off);
      if (od > bd || (od == bd && oi < bi)) { bd = od; bi = oi; }
    }
    if (lane == 0)
      wslot[wv] = ((u64)__float_as_uint(bd) << 13) | (u64)(unsigned)(8191 - bi);
    __syncthreads();

    if (wv == 0) {
      u64 v = (lane < 16) ? wslot[lane] : 0ULL;
      #pragma unroll
      for (int off = 8; off >= 1; off >>= 1) {
        u64 o = __shfl_xor(v, off, 16);
        if (o > v) v = o;
      }
      if (lane == 0) {
        int qi = 8191 - (int)(v & 0x1FFFu);
        qidx_sh = qi;
        fps_idx[s * M_PER_SEG + t] = qi;
      }
    }
    __syncthreads();
    q = qidx_sh;
  }
}

// ===========================================================================
// FALLBACK (tier C): distributed MALL-sync FPS, point packed as fp16 in
// NAMED uint2 registers (32 VGPR) -> nothing indexable, nothing to spill.
// ===========================================================================
__global__ __attribute__((amdgpu_waves_per_eu(2, 2)))
__launch_bounds__(FPS_THREADS)
void fps_kernel(const float* __restrict__ xyz, const float* __restrict__ feat,
                u64* __restrict__ cand, int* __restrict__ fps_idx)
{
#pragma clang fp contract(off)
  __shared__ u64 wslot[FPS_WAVES];
  __shared__ int qidx_sh;

  const int tid  = threadIdx.x;
  const int lane = tid & 63;
  const int wv   = tid >> 6;
  const int s    = blockIdx.x >> 4;
  const int wg   = blockIdx.x & 15;
  const int pl   = wg * FPS_THREADS + tid;
  const size_t gr = (size_t)(s * SEG_N + pl);

  // my point: xyz f32, feat as 16 named uint2 of fp16 pairs
  float px, py, pz;
#define DECLP(k) uint2 pp##k;
  REP16(DECLP)
  px = xyz[gr*3+0]; py = xyz[gr*3+1]; pz = xyz[gr*3+2];
  {
    const float4* fr = (const float4*)(feat + gr * CFEAT);
#define LOADP(k) { float4 v = fr[k]; pp##k.x = pk2(v.x, v.y); pp##k.y = pk2(v.z, v.w); }
    REP16(LOADP)
  }

  // query q: f32 named registers, reloaded every step
  float qx, qy, qz;
#define DECLQ(k) float4 qf##k;
  REP16(DECLQ)
#define LOADQ1(k) qf##k = frq[k];
#define LOAD_Q(qb) { \
    qx = xyz[(qb)*3+0]; qy = xyz[(qb)*3+1]; qz = xyz[(qb)*3+2]; \
    const float4* frq = (const float4*)(feat + (qb) * CFEAT); \
    REP16(LOADQ1) }

  LOAD_Q((size_t)(s * SEG_N))
  if (tid == 0 && wg == 0) fps_idx[s * M_PER_SEG] = 0;

  float D = 1e10f;

  for (int t = 1; t < M_PER_SEG; ++t) {
    float r0=0.f, r1=0.f, r2=0.f, r3=0.f, r4=0.f, r5=0.f, r6=0.f, r7=0.f;
    {
      float tt;
      tt = px - qx; r0 += tt*tt;
      tt = py - qy; r1 += tt*tt;
      tt = pz - qz; r2 += tt*tt;
    }
#define DE(k) { float2 ab = up2(pp##k.x), cd = up2(pp##k.y); \
                float t0 = ab.x - qf##k.x; r3 += t0*t0; \
                float t1 = ab.y - qf##k.y; r4 += t1*t1; \
                float t2 = cd.x - qf##k.z; r5 += t2*t2; \
                float t3 = cd.y - qf##k.w; r6 += t3*t3; }
#define DO(k) { float2 ab = up2(pp##k.x), cd = up2(pp##k.y); \
                float t0 = ab.x - qf##k.x; r7 += t0*t0; \
                float t1 = ab.y - qf##k.y; r0 += t1*t1; \
                float t2 = cd.x - qf##k.z; r1 += t2*t2; \
                float t3 = cd.y - qf##k.w; r2 += t3*t3; }
    REP16_EO(DE, DO)
    float a = ((r0+r1)+(r2+r3)) + ((r4+r5)+(r6+r7));
    D = fminf(D, a);

    float bd = D; int bi = pl;
    #pragma unroll
    for (int off = 32; off >= 1; off >>= 1) {
      float od = __shfl_xor(bd, off);
      int   oi = __shfl_xor(bi, off);
      if (od > bd || (od == bd && oi < bi)) { bd = od; bi = oi; }
    }
    if (lane == 0)
      wslot[wv] = ((u64)__float_as_uint(bd) << 13) | (u64)(unsigned)(8191 - bi);
    __syncthreads();

    if (wv == 0) {
      u64 w = (lane < FPS_WAVES) ? wslot[lane] : 0ULL;
      #pragma unroll
      for (int off = 4; off >= 1; off >>= 1) {
        u64 o = __shfl_xor(w, off, 8);
        if (o > w) w = o;
      }
      u64* base = &cand[(((unsigned)t & 1u) * NSEG + s) * SLOT_STRIDE];
      if (lane == 0)
        __hip_atomic_store(&base[wg], ((u64)(unsigned)t << 45) | w, RLX, AG);

      u64 v = 0;
      if (lane < FPS_WGS_PER_SEG) {
        v = __hip_atomic_load(&base[lane], RLX, AG);
        while ((unsigned)(v >> 45) != (unsigned)t) {
          __builtin_amdgcn_s_sleep(1);
          v = __hip_atomic_load(&base[lane], RLX, AG);
        }
      }
      #pragma unroll
      for (int off = 8; off >= 1; off >>= 1) {
        u64 o = __shfl_xor(v, off, 16);
        if (o > v) v = o;
      }
      int qi = 8191 - (int)(v & 0x1FFFu);
      if (lane == 0) {
        qidx_sh = qi;
        if (wg == 0) fps_idx[s * M_PER_SEG + t] = qi;
      }
    }
    __syncthreads();

    LOAD_Q((size_t)(s * SEG_N + qidx_sh))
  }
}

// ---------------------------------------------------------------------------
__global__ void gather_kernel(const float* __restrict__ xyz, const float* __restrict__ vel,
                              const int* __restrict__ fps_idx, float* __restrict__ out)
{
  int i = blockIdx.x * 256 + threadIdx.x;
  if (i >= M_TOTAL) return;
  int s = i >> 11, r = i & 2047;
  int g = s * SEG_N + (fps_idx[s * M_PER_SEG + r] & 8191);
  out[OUT_XYZ + i*3 + 0] = xyz[(size_t)g*3 + 0];
  out[OUT_XYZ + i*3 + 1] = xyz[(size_t)g*3 + 1];
  out[OUT_XYZ + i*3 + 2] = xyz[(size_t)g*3 + 2];
  out[OUT_VEL + i*3 + 0] = vel[(size_t)g*3 + 0];
  out[OUT_VEL + i*3 + 1] = vel[(size_t)g*3 + 1];
  out[OUT_VEL + i*3 + 2] = vel[(size_t)g*3 + 2];
  if (i == 0) { out[OUT_OFF] = 2048.0f; out[OUT_OFF + 1] = 4096.0f; }
}

// ---------------------------------------------------------------------------
#define KNN_TILE 1024
__global__ __launch_bounds__(256)
void knn_kernel(const float* __restrict__ xyz, const float* __restrict__ out,
                int* __restrict__ knn)
{
  __shared__ float px[KNN_TILE], py[KNN_TILE], pz[KNN_TILE];
  __shared__ float ldK[16][16][16];
  __shared__ float Tq[16];
  __shared__ float dbuf[16][24];
  __shared__ int   cbuf[16][24];
  __shared__ int   cnt[16];

  const int tid = threadIdx.x;
  const int ql = tid >> 4, j = tid & 15;
  const int qg = blockIdx.x * 16 + ql;
  const int s  = qg >> 11;
  const float qx = out[OUT_XYZ + qg*3 + 0];
  const float qy = out[OUT_XYZ + qg*3 + 1];
  const float qz = out[OUT_XYZ + qg*3 + 2];
  const float sq = qx*qx + qy*qy + qz*qz;

  float K[16];
  #pragma unroll
  for (int r = 0; r < 16; ++r) K[r] = 3.4e38f;

  for (int tile = 0; tile < SEG_N / KNN_TILE; ++tile) {
    __syncthreads();
    for (int u = tid; u < KNN_TILE; u += 256) {
      size_t g = (size_t)(s * SEG_N + tile * KNN_TILE + u);
      px[u] = xyz[g*3+0]; py[u] = xyz[g*3+1]; pz[u] = xyz[g*3+2];
    }
    __syncthreads();
    #pragma unroll 4
    for (int i = 0; i < KNN_TILE / 16; ++i) {
      int c = i * 16 + j;
      float x = px[c], y = py[c], z = pz[c];
      float sp  = x*x + y*y + z*z;
      float dot = qx*x + qy*y + qz*z;
      float d2  = (sq + sp) - 2.0f * dot;
      #pragma unroll
      for (int r = 15; r >= 1; --r)
        K[r] = fminf(fmaxf(d2, K[r-1]), K[r]);
      K[0] = fminf(K[0], d2);
    }
  }
  #pragma unroll
  for (int r = 0; r < 16; ++r) ldK[ql][j][r] = K[r];
  __syncthreads();

  {
    int head = 0;
    float T = 3.4e38f;
    for (int r = 0; r < 16; ++r) {
      float val = (head < 16) ? ldK[ql][j][head] : 3.4e38f;
      float mv = val; int ml = j;
      #pragma unroll
      for (int off = 8; off >= 1; off >>= 1) {
        float ov = __shfl_xor(mv, off, 16);
        int   ol = __shfl_xor(ml, off, 16);
        if (ov < mv || (ov == mv && ol < ml)) { mv = ov; ml = ol; }
      }
      if (j == ml) head++;
      T = mv;
    }
    if (j == 0) { Tq[ql] = T; cnt[ql] = 0; }
  }
  __syncthreads();
  const float T  = Tq[ql];
  const float Tm = T + fabsf(T) * 1e-6f + 1e-30f;

  for (int tile = 0; tile < SEG_N / KNN_TILE; ++tile) {
    __syncthreads();
    for (int u = tid; u < KNN_TILE; u += 256) {
      size_t g = (size_t)(s * SEG_N + tile * KNN_TILE + u);
      px[u] = xyz[g*3+0]; py[u] = xyz[g*3+1]; pz[u] = xyz[g*3+2];
    }
    __syncthreads();
    for (int i = 0; i < KNN_TILE / 16; ++i) {
      int c = i * 16 + j;
      float x = px[c], y = py[c], z = pz[c];
      float sp  = x*x + y*y + z*z;
      float dot = qx*x + qy*y + qz*z;
      float d2  = (sq + sp) - 2.0f * dot;
      if (d2 <= Tm) {
        int pos = atomicAdd(&cnt[ql], 1);
        if (pos < 24) { dbuf[ql][pos] = d2; cbuf[ql][pos] = tile * KNN_TILE + c; }
      }
    }
  }
  __syncthreads();

  if (j == 0) {
    int n = cnt[ql]; if (n > 24) n = 24;
    for (int r = 0; r < NSAMPLE; ++r) {
      float bv = 3.4e38f; int bc = 0, bp = -1;
      for (int e = 0; e < n; ++e) {
        float dv = dbuf[ql][e]; int cc = cbuf[ql][e];
        if (dv < bv || (dv == bv && cc < bc)) { bv = dv; bc = cc; bp = e; }
      }
      if (bp >= 0) dbuf[ql][bp] = 3.4e38f;
      knn[qg * NSAMPLE + r] = bc;
    }
  }
}

// ---------------------------------------------------------------------------
__global__ __launch_bounds__(128)
void gemm_kernel(const float* __restrict__ feat, const float* __restrict__ W,
                 const int* __restrict__ knn, float* __restrict__ out)
{
  __shared__ __align__(16) float f[NSAMPLE][CFEAT];
  __shared__ int kid[NSAMPLE];
  const int tid = threadIdx.x;
  const int q = blockIdx.x;
  const int s = q >> 11;
  if (tid < NSAMPLE) kid[tid] = knn[q * NSAMPLE + tid] & 8191;
  __syncthreads();
  for (int e = tid; e < NSAMPLE * CFEAT; e += 128) {
    int k = e >> 6, c = e & 63;
    f[k][c] = feat[(size_t)(s * SEG_N + kid[k]) * CFEAT + c];
  }
  float4 w[16];
  const float4* Wrow = (const float4*)(W + (size_t)tid * CFEAT);
  #pragma unroll
  for (int c4 = 0; c4 < 16; ++c4) w[c4] = Wrow[c4];
  __syncthreads();

  float m = -3.4e38f;
  #pragma unroll
  for (int k = 0; k < NSAMPLE; ++k) {
    float acc = 0.f;
    const float4* frow = (const float4*)&f[k][0];
    #pragma unroll
    for (int c4 = 0; c4 < 16; ++c4) {
      float4 fv = frow[c4];
      acc += fv.x * w[c4].x + fv.y * w[c4].y + fv.z * w[c4].z + fv.w * w[c4].w;
    }
    m = fmaxf(m, acc);
  }
  out[OUT_FEAT + (size_t)q * COUT + tid] = fmaxf(m, 0.f);
}

// ---------------------------------------------------------------------------
extern "C" void kernel_launch(void* const* d_in, const int* in_sizes, int n_in,
                              void* d_out, int out_size, void* d_ws, size_t ws_size,
                              hipStream_t stream)
{
  const float* xyz  = (const float*)d_in[0];
  const float* feat = (const float*)d_in[1];
  // d_in[2] = offset (segment sizes fixed by the problem)
  const float* vel  = (const float*)d_in[3];
  const float* W    = (const float*)d_in[4];
  float* out = (float*)d_out;
  char*  ws  = (char*)d_ws;
  u64* cand    = (u64*)(ws + WS_CAND);
  int* fps_idx = (int*)(ws + WS_FPS);
  int* knn     = (int*)(ws + WS_KNN);

  const int GRAM_GRID = (SEG_N / 128) * (SEG_N / 64);   // 8192

  if (ws_size >= (size_t)WS_D2 + 2 * D2_SEG) {
    // Tier A: both segments resident; fps WGs run in parallel
    float* sq = (float*)(ws + WS_SQ);
    unsigned short* d2m = (unsigned short*)(ws + WS_D2);
    norm_kernel<<<(NSEG * SEG_N) / 256, 256, 0, stream>>>(xyz, feat, sq);
    gram_kernel<<<GRAM_GRID, 256, 0, stream>>>(xyz, feat, sq, d2m, 0);
    gram_kernel<<<GRAM_GRID, 256, 0, stream>>>(xyz, feat, sq,
                                               d2m + SEG_N * (size_t)SEG_N, 1);
    fps_fast_kernel<<<NSEG, 1024, 0, stream>>>(d2m, 0, (size_t)SEG_N * SEG_N,
                                               fps_idx);
  } else if (ws_size >= (size_t)WS_D2 + D2_SEG) {
    // Tier B: one matrix buffer, segments sequential (stream-ordered)
    float* sq = (float*)(ws + WS_SQ);
    unsigned short* d2m = (unsigned short*)(ws + WS_D2);
    norm_kernel<<<(NSEG * SEG_N) / 256, 256, 0, stream>>>(xyz, feat, sq);
    gram_kernel<<<GRAM_GRID, 256, 0, stream>>>(xyz, feat, sq, d2m, 0);
    fps_fast_kernel<<<1, 1024, 0, stream>>>(d2m, 0, 0, fps_idx);
    gram_kernel<<<GRAM_GRID, 256, 0, stream>>>(xyz, feat, sq, d2m, 1);
    fps_fast_kernel<<<1, 1024, 0, stream>>>(d2m, 1, 0, fps_idx);
  } else {
    // Tier C: distributed MALL-sync FPS (fp16-packed registers)
    hipMemsetAsync(cand, 0, 512, stream);
    fps_kernel<<<NSEG * FPS_WGS_PER_SEG, FPS_THREADS, 0, stream>>>(
        xyz, feat, cand, fps_idx);
  }
  gather_kernel<<<M_TOTAL / 256, 256, 0, stream>>>(xyz, vel, fps_idx, out);
  knn_kernel<<<M_TOTAL / 16, 256, 0, stream>>>(xyz, out, knn);
  gemm_kernel<<<M_TOTAL, 128, 0, stream>>>(feat, W, knn, out);
}

// Round 12
// 2532.839 us; speedup vs baseline: 2.6084x; 2.6084x over previous
//
#include <hip/hip_runtime.h>
#include <hip/hip_fp16.h>

typedef unsigned long long u64;

#define SEG_N     8192
#define NSEG      2
#define M_PER_SEG 2048
#define M_TOTAL   4096
#define CFEAT     64
#define COUT      128
#define NSAMPLE   16

#define FPS_WGS_PER_SEG 16
#define FPS_THREADS     512
#define FPS_WAVES       8
#define SLOT_STRIDE     16    // u64s per (parity,seg) row = 128B line

// d_out layout (floats): new_xyz | new_feat | new_offset | new_vel
#define OUT_XYZ   0
#define OUT_FEAT  12288      // 4096*3
#define OUT_OFF   536576     // + 4096*128
#define OUT_VEL   536578     // + 2

// d_ws layout (bytes)
#define WS_CAND 0            // u64 cand[2][2][16]  (fallback sync slots)
#define WS_FPS  512          // int fps_idx[2][2048]
#define WS_KNN  16896        // int knn[4096][16]
#define WS_SQ   (1<<19)      // float sq[16384]
#define WS_D2   (1<<20)      // u8 D2 matrix region (2 x 67MB)
#define D2_SEG8 ((size_t)SEG_N * SEG_N)       // 67 MB per segment (u8)

#define AG  __HIP_MEMORY_SCOPE_AGENT
#define RLX __ATOMIC_RELAXED

#define REP16(M) M(0) M(1) M(2) M(3) M(4) M(5) M(6) M(7) \
                 M(8) M(9) M(10) M(11) M(12) M(13) M(14) M(15)
#define REP16_EO(E,O) E(0) O(1) E(2) O(3) E(4) O(5) E(6) O(7) \
                      E(8) O(9) E(10) O(11) E(12) O(13) E(14) O(15)

__device__ __forceinline__ unsigned pk2(float a, float b) {
  __half2 h = __floats2half2_rn(a, b);
  unsigned u; __builtin_memcpy(&u, &h, 4); return u;
}
__device__ __forceinline__ float2 up2(unsigned u) {
  __half2 h; __builtin_memcpy(&h, &u, 4);
  return __half22float2(h);
}

// ===========================================================================
// FAST PATH: u8 d^2 matrix (scale 1.0, clamp 255), 67MB/segment -> both
// segments fit in 134MB (same ws bound the u16 single-segment tier proved),
// AND the whole matrix is L3-resident (134 < 256MB) -> row loads are
// Infinity-Cache latency, not HBM. FPS runs both segments in parallel,
// one WG each, zero cross-WG sync.
// ===========================================================================

__global__ __launch_bounds__(256)
void norm_kernel(const float* __restrict__ xyz, const float* __restrict__ feat,
                 float* __restrict__ sq)
{
  int i = blockIdx.x * 256 + threadIdx.x;
  if (i >= NSEG * SEG_N) return;
  float a0 = xyz[(size_t)i*3+0], a1 = xyz[(size_t)i*3+1], a2 = xyz[(size_t)i*3+2];
  float acc = a0*a0 + a1*a1 + a2*a2;
  const float4* fr = (const float4*)(feat + (size_t)i * CFEAT);
  #pragma unroll
  for (int k = 0; k < 16; ++k) {
    float4 v = fr[k];
    acc += v.x*v.x + v.y*v.y + v.z*v.z + v.w*v.w;
  }
  sq[i] = acc;
}

// rank-67 GEMM -> u8 d^2 tile (128q x 64p per block), both segments.
__global__ __launch_bounds__(256)
void gram8_kernel(const float* __restrict__ xyz, const float* __restrict__ feat,
                  const float* __restrict__ sq, unsigned char* __restrict__ d2m)
{
  __shared__ float Aq[68][132];
  __shared__ float Ap[68][68];

  const int b   = blockIdx.x;
  const int s   = b >> 13;              // 8192 blocks per segment
  const int rem = b & 8191;
  const int tq  = rem >> 7;             // 0..63  (q tiles of 128)
  const int tp  = rem & 127;            // 0..127 (p tiles of 64)
  const int q0  = tq * 128, p0 = tp * 64;
  const int tid = threadIdx.x;
  unsigned char* d2seg = d2m + (size_t)s * D2_SEG8;

  for (int e = tid; e < 128 * 64; e += 256) {
    int r = e >> 6, c = e & 63;
    Aq[3 + c][r] = feat[(size_t)(s * SEG_N + q0 + r) * CFEAT + c];
  }
  for (int e = tid; e < 128 * 3; e += 256) {
    int r = e / 3, d = e - r * 3;
    Aq[d][r] = xyz[(size_t)(s * SEG_N + q0 + r) * 3 + d];
  }
  for (int e = tid; e < 64 * 64; e += 256) {
    int r = e >> 6, c = e & 63;
    Ap[3 + c][r] = feat[(size_t)(s * SEG_N + p0 + r) * CFEAT + c];
  }
  for (int e = tid; e < 64 * 3; e += 256) {
    int r = e / 3, d = e - r * 3;
    Ap[d][r] = xyz[(size_t)(s * SEG_N + p0 + r) * 3 + d];
  }
  __syncthreads();

  const int ty = tid >> 4, tx = tid & 15;   // 8q x 4p per thread
  float acc[8][4];
  #pragma unroll
  for (int i = 0; i < 8; ++i)
    #pragma unroll
    for (int j = 0; j < 4; ++j) acc[i][j] = 0.f;

  for (int k = 0; k < 67; ++k) {
    const float* aq = &Aq[k][ty * 8];
    const float* bp = &Ap[k][tx * 4];
    float a[8], bb[4];
    #pragma unroll
    for (int i = 0; i < 8; ++i) a[i] = aq[i];
    #pragma unroll
    for (int j = 0; j < 4; ++j) bb[j] = bp[j];
    #pragma unroll
    for (int i = 0; i < 8; ++i)
      #pragma unroll
      for (int j = 0; j < 4; ++j) acc[i][j] += a[i] * bb[j];
  }

  float sp[4];
  #pragma unroll
  for (int j = 0; j < 4; ++j) sp[j] = sq[s * SEG_N + p0 + tx * 4 + j];

  #pragma unroll
  for (int i = 0; i < 8; ++i) {
    int qrow = q0 + ty * 8 + i;
    float sqq = sq[s * SEG_N + qrow];
    unsigned o[4];
    #pragma unroll
    for (int j = 0; j < 4; ++j) {
      float d2 = sqq + sp[j] - 2.f * acc[i][j];
      d2 = fmaxf(d2, 0.f);
      o[j] = __float2uint_rn(fminf(d2, 255.f));
    }
    unsigned pkd = o[0] | (o[1] << 8) | (o[2] << 16) | (o[3] << 24);
    *(unsigned*)&d2seg[((size_t)qrow << 13) + (p0 + tx * 4)] = pkd;
  }
}

// FPS from the u8 matrix: one WG per segment (grid=2, parallel), 1024 threads
// x 8 points. Per step: one 8B row-slice load (L3-hot), 8 u32 mins, packed
// u32 candidate (dist<<13 | 8191-idx), 64-lane butterfly, parity-double-
// buffered 16-slot LDS funnel, ONE barrier, all waves reduce redundantly.
__global__ __launch_bounds__(1024)
void fps_fast8_kernel(const unsigned char* __restrict__ d2m,
                      int* __restrict__ fps_idx)
{
  __shared__ unsigned wslot[2][16];

  const int tid  = threadIdx.x;
  const int lane = tid & 63;
  const int wv   = tid >> 6;
  const int s    = blockIdx.x;
  const int p0   = tid * 8;
  const unsigned idx0 = 8191 - p0;          // inv-index of my point k=0
  const unsigned char* base_s = d2m + (size_t)s * D2_SEG8;

  unsigned D0=255u,D1=255u,D2v=255u,D3=255u,D4=255u,D5=255u,D6=255u,D7=255u;

  if (tid == 0) fps_idx[s * M_PER_SEG] = 0;
  int q = 0;

  for (int t = 1; t < M_PER_SEG; ++t) {
    uint2 w = *(const uint2*)(base_s + ((size_t)q << 13) + p0);
    unsigned a = w.x, b = w.y;
    D0 = min(D0,  a        & 255u);
    D1 = min(D1, (a >>  8) & 255u);
    D2v= min(D2v,(a >> 16) & 255u);
    D3 = min(D3,  a >> 24);
    D4 = min(D4,  b        & 255u);
    D5 = min(D5, (b >>  8) & 255u);
    D6 = min(D6, (b >> 16) & 255u);
    D7 = min(D7,  b >> 24);

    // packed candidates: dist<<13 | inv-idx  (ties -> lowest point index)
    unsigned c = (D0 << 13) | idx0;
    c = max(c, (D1 << 13) | (idx0 - 1u));
    c = max(c, (D2v<< 13) | (idx0 - 2u));
    c = max(c, (D3 << 13) | (idx0 - 3u));
    c = max(c, (D4 << 13) | (idx0 - 4u));
    c = max(c, (D5 << 13) | (idx0 - 5u));
    c = max(c, (D6 << 13) | (idx0 - 6u));
    c = max(c, (D7 << 13) | (idx0 - 7u));

    #pragma unroll
    for (int off = 32; off >= 1; off >>= 1)
      c = max(c, (unsigned)__shfl_xor((int)c, off));
    if (lane == 0) wslot[t & 1][wv] = c;
    __syncthreads();                       // single barrier per step

    unsigned v = wslot[t & 1][lane & 15];
    #pragma unroll
    for (int off = 8; off >= 1; off >>= 1)
      v = max(v, (unsigned)__shfl_xor((int)v, off, 16));
    q = 8191 - (int)(v & 0x1FFFu);
    if (tid == 0) fps_idx[s * M_PER_SEG + t] = q;
  }
}

// ===========================================================================
// FALLBACK (tier C): distributed MALL-sync FPS, fp16-packed named registers.
// ===========================================================================
__global__ __attribute__((amdgpu_waves_per_eu(2, 2)))
__launch_bounds__(FPS_THREADS)
void fps_kernel(const float* __restrict__ xyz, const float* __restrict__ feat,
                u64* __restrict__ cand, int* __restrict__ fps_idx)
{
#pragma clang fp contract(off)
  __shared__ u64 wslot[FPS_WAVES];
  __shared__ int qidx_sh;

  const int tid  = threadIdx.x;
  const int lane = tid & 63;
  const int wv   = tid >> 6;
  const int s    = blockIdx.x >> 4;
  const int wg   = blockIdx.x & 15;
  const int pl   = wg * FPS_THREADS + tid;
  const size_t gr = (size_t)(s * SEG_N + pl);

  float px, py, pz;
#define DECLP(k) uint2 pp##k;
  REP16(DECLP)
  px = xyz[gr*3+0]; py = xyz[gr*3+1]; pz = xyz[gr*3+2];
  {
    const float4* fr = (const float4*)(feat + gr * CFEAT);
#define LOADP(k) { float4 v = fr[k]; pp##k.x = pk2(v.x, v.y); pp##k.y = pk2(v.z, v.w); }
    REP16(LOADP)
  }

  float qx, qy, qz;
#define DECLQ(k) float4 qf##k;
  REP16(DECLQ)
#define LOADQ1(k) qf##k = frq[k];
#define LOAD_Q(qb) { \
    qx = xyz[(qb)*3+0]; qy = xyz[(qb)*3+1]; qz = xyz[(qb)*3+2]; \
    const float4* frq = (const float4*)(feat + (qb) * CFEAT); \
    REP16(LOADQ1) }

  LOAD_Q((size_t)(s * SEG_N))
  if (tid == 0 && wg == 0) fps_idx[s * M_PER_SEG] = 0;

  float D = 1e10f;

  for (int t = 1; t < M_PER_SEG; ++t) {
    float r0=0.f, r1=0.f, r2=0.f, r3=0.f, r4=0.f, r5=0.f, r6=0.f, r7=0.f;
    {
      float tt;
      tt = px - qx; r0 += tt*tt;
      tt = py - qy; r1 += tt*tt;
      tt = pz - qz; r2 += tt*tt;
    }
#define DE(k) { float2 ab = up2(pp##k.x), cd = up2(pp##k.y); \
                float t0 = ab.x - qf##k.x; r3 += t0*t0; \
                float t1 = ab.y - qf##k.y; r4 += t1*t1; \
                float t2 = cd.x - qf##k.z; r5 += t2*t2; \
                float t3 = cd.y - qf##k.w; r6 += t3*t3; }
#define DO(k) { float2 ab = up2(pp##k.x), cd = up2(pp##k.y); \
                float t0 = ab.x - qf##k.x; r7 += t0*t0; \
                float t1 = ab.y - qf##k.y; r0 += t1*t1; \
                float t2 = cd.x - qf##k.z; r1 += t2*t2; \
                float t3 = cd.y - qf##k.w; r2 += t3*t3; }
    REP16_EO(DE, DO)
    float a = ((r0+r1)+(r2+r3)) + ((r4+r5)+(r6+r7));
    D = fminf(D, a);

    float bd = D; int bi = pl;
    #pragma unroll
    for (int off = 32; off >= 1; off >>= 1) {
      float od = __shfl_xor(bd, off);
      int   oi = __shfl_xor(bi, off);
      if (od > bd || (od == bd && oi < bi)) { bd = od; bi = oi; }
    }
    if (lane == 0)
      wslot[wv] = ((u64)__float_as_uint(bd) << 13) | (u64)(unsigned)(8191 - bi);
    __syncthreads();

    if (wv == 0) {
      u64 w = (lane < FPS_WAVES) ? wslot[lane] : 0ULL;
      #pragma unroll
      for (int off = 4; off >= 1; off >>= 1) {
        u64 o = __shfl_xor(w, off, 8);
        if (o > w) w = o;
      }
      u64* base = &cand[(((unsigned)t & 1u) * NSEG + s) * SLOT_STRIDE];
      if (lane == 0)
        __hip_atomic_store(&base[wg], ((u64)(unsigned)t << 45) | w, RLX, AG);

      u64 v = 0;
      if (lane < FPS_WGS_PER_SEG) {
        v = __hip_atomic_load(&base[lane], RLX, AG);
        while ((unsigned)(v >> 45) != (unsigned)t) {
          __builtin_amdgcn_s_sleep(1);
          v = __hip_atomic_load(&base[lane], RLX, AG);
        }
      }
      #pragma unroll
      for (int off = 8; off >= 1; off >>= 1) {
        u64 o = __shfl_xor(v, off, 16);
        if (o > v) v = o;
      }
      int qi = 8191 - (int)(v & 0x1FFFu);
      if (lane == 0) {
        qidx_sh = qi;
        if (wg == 0) fps_idx[s * M_PER_SEG + t] = qi;
      }
    }
    __syncthreads();

    LOAD_Q((size_t)(s * SEG_N + qidx_sh))
  }
}

// ---------------------------------------------------------------------------
__global__ void gather_kernel(const float* __restrict__ xyz, const float* __restrict__ vel,
                              const int* __restrict__ fps_idx, float* __restrict__ out)
{
  int i = blockIdx.x * 256 + threadIdx.x;
  if (i >= M_TOTAL) return;
  int s = i >> 11, r = i & 2047;
  int g = s * SEG_N + (fps_idx[s * M_PER_SEG + r] & 8191);
  out[OUT_XYZ + i*3 + 0] = xyz[(size_t)g*3 + 0];
  out[OUT_XYZ + i*3 + 1] = xyz[(size_t)g*3 + 1];
  out[OUT_XYZ + i*3 + 2] = xyz[(size_t)g*3 + 2];
  out[OUT_VEL + i*3 + 0] = vel[(size_t)g*3 + 0];
  out[OUT_VEL + i*3 + 1] = vel[(size_t)g*3 + 1];
  out[OUT_VEL + i*3 + 2] = vel[(size_t)g*3 + 2];
  if (i == 0) { out[OUT_OFF] = 2048.0f; out[OUT_OFF + 1] = 4096.0f; }
}

// ---------------------------------------------------------------------------
#define KNN_TILE 1024
__global__ __launch_bounds__(256)
void knn_kernel(const float* __restrict__ xyz, const float* __restrict__ out,
                int* __restrict__ knn)
{
  __shared__ float px[KNN_TILE], py[KNN_TILE], pz[KNN_TILE];
  __shared__ float ldK[16][16][16];
  __shared__ float Tq[16];
  __shared__ float dbuf[16][24];
  __shared__ int   cbuf[16][24];
  __shared__ int   cnt[16];

  const int tid = threadIdx.x;
  const int ql = tid >> 4, j = tid & 15;
  const int qg = blockIdx.x * 16 + ql;
  const int s  = qg >> 11;
  const float qx = out[OUT_XYZ + qg*3 + 0];
  const float qy = out[OUT_XYZ + qg*3 + 1];
  const float qz = out[OUT_XYZ + qg*3 + 2];
  const float sq = qx*qx + qy*qy + qz*qz;

  float K[16];
  #pragma unroll
  for (int r = 0; r < 16; ++r) K[r] = 3.4e38f;

  for (int tile = 0; tile < SEG_N / KNN_TILE; ++tile) {
    __syncthreads();
    for (int u = tid; u < KNN_TILE; u += 256) {
      size_t g = (size_t)(s * SEG_N + tile * KNN_TILE + u);
      px[u] = xyz[g*3+0]; py[u] = xyz[g*3+1]; pz[u] = xyz[g*3+2];
    }
    __syncthreads();
    #pragma unroll 4
    for (int i = 0; i < KNN_TILE / 16; ++i) {
      int c = i * 16 + j;
      float x = px[c], y = py[c], z = pz[c];
      float sp  = x*x + y*y + z*z;
      float dot = qx*x + qy*y + qz*z;
      float d2  = (sq + sp) - 2.0f * dot;
      #pragma unroll
      for (int r = 15; r >= 1; --r)
        K[r] = fminf(fmaxf(d2, K[r-1]), K[r]);
      K[0] = fminf(K[0], d2);
    }
  }
  #pragma unroll
  for (int r = 0; r < 16; ++r) ldK[ql][j][r] = K[r];
  __syncthreads();

  {
    int head = 0;
    float T = 3.4e38f;
    for (int r = 0; r < 16; ++r) {
      float val = (head < 16) ? ldK[ql][j][head] : 3.4e38f;
      float mv = val; int ml = j;
      #pragma unroll
      for (int off = 8; off >= 1; off >>= 1) {
        float ov = __shfl_xor(mv, off, 16);
        int   ol = __shfl_xor(ml, off, 16);
        if (ov < mv || (ov == mv && ol < ml)) { mv = ov; ml = ol; }
      }
      if (j == ml) head++;
      T = mv;
    }
    if (j == 0) { Tq[ql] = T; cnt[ql] = 0; }
  }
  __syncthreads();
  const float T  = Tq[ql];
  const float Tm = T + fabsf(T) * 1e-6f + 1e-30f;

  for (int tile = 0; tile < SEG_N / KNN_TILE; ++tile) {
    __syncthreads();
    for (int u = tid; u < KNN_TILE; u += 256) {
      size_t g = (size_t)(s * SEG_N + tile * KNN_TILE + u);
      px[u] = xyz[g*3+0]; py[u] = xyz[g*3+1]; pz[u] = xyz[g*3+2];
    }
    __syncthreads();
    for (int i = 0; i < KNN_TILE / 16; ++i) {
      int c = i * 16 + j;
      float x = px[c], y = py[c], z = pz[c];
      float sp  = x*x + y*y + z*z;
      float dot = qx*x + qy*y + qz*z;
      float d2  = (sq + sp) - 2.0f * dot;
      if (d2 <= Tm) {
        int pos = atomicAdd(&cnt[ql], 1);
        if (pos < 24) { dbuf[ql][pos] = d2; cbuf[ql][pos] = tile * KNN_TILE + c; }
      }
    }
  }
  __syncthreads();

  if (j == 0) {
    int n = cnt[ql]; if (n > 24) n = 24;
    for (int r = 0; r < NSAMPLE; ++r) {
      float bv = 3.4e38f; int bc = 0, bp = -1;
      for (int e = 0; e < n; ++e) {
        float dv = dbuf[ql][e]; int cc = cbuf[ql][e];
        if (dv < bv || (dv == bv && cc < bc)) { bv = dv; bc = cc; bp = e; }
      }
      if (bp >= 0) dbuf[ql][bp] = 3.4e38f;
      knn[qg * NSAMPLE + r] = bc;
    }
  }
}

// ---------------------------------------------------------------------------
__global__ __launch_bounds__(128)
void gemm_kernel(const float* __restrict__ feat, const float* __restrict__ W,
                 const int* __restrict__ knn, float* __restrict__ out)
{
  __shared__ __align__(16) float f[NSAMPLE][CFEAT];
  __shared__ int kid[NSAMPLE];
  const int tid = threadIdx.x;
  const int q = blockIdx.x;
  const int s = q >> 11;
  if (tid < NSAMPLE) kid[tid] = knn[q * NSAMPLE + tid] & 8191;
  __syncthreads();
  for (int e = tid; e < NSAMPLE * CFEAT; e += 128) {
    int k = e >> 6, c = e & 63;
    f[k][c] = feat[(size_t)(s * SEG_N + kid[k]) * CFEAT + c];
  }
  float4 w[16];
  const float4* Wrow = (const float4*)(W + (size_t)tid * CFEAT);
  #pragma unroll
  for (int c4 = 0; c4 < 16; ++c4) w[c4] = Wrow[c4];
  __syncthreads();

  float m = -3.4e38f;
  #pragma unroll
  for (int k = 0; k < NSAMPLE; ++k) {
    float acc = 0.f;
    const float4* frow = (const float4*)&f[k][0];
    #pragma unroll
    for (int c4 = 0; c4 < 16; ++c4) {
      float4 fv = frow[c4];
      acc += fv.x * w[c4].x + fv.y * w[c4].y + fv.z * w[c4].z + fv.w * w[c4].w;
    }
    m = fmaxf(m, acc);
  }
  out[OUT_FEAT + (size_t)q * COUT + tid] = fmaxf(m, 0.f);
}

// ---------------------------------------------------------------------------
extern "C" void kernel_launch(void* const* d_in, const int* in_sizes, int n_in,
                              void* d_out, int out_size, void* d_ws, size_t ws_size,
                              hipStream_t stream)
{
  const float* xyz  = (const float*)d_in[0];
  const float* feat = (const float*)d_in[1];
  // d_in[2] = offset (segment sizes fixed by the problem)
  const float* vel  = (const float*)d_in[3];
  const float* W    = (const float*)d_in[4];
  float* out = (float*)d_out;
  char*  ws  = (char*)d_ws;
  u64* cand    = (u64*)(ws + WS_CAND);
  int* fps_idx = (int*)(ws + WS_FPS);
  int* knn     = (int*)(ws + WS_KNN);

  if (ws_size >= (size_t)WS_D2 + NSEG * D2_SEG8) {
    // u8 matrix path: both segments resident + L3-cached, FPS in parallel
    float* sq = (float*)(ws + WS_SQ);
    unsigned char* d2m = (unsigned char*)(ws + WS_D2);
    norm_kernel<<<(NSEG * SEG_N) / 256, 256, 0, stream>>>(xyz, feat, sq);
    gram8_kernel<<<NSEG * (SEG_N / 128) * (SEG_N / 64), 256, 0, stream>>>(
        xyz, feat, sq, d2m);
    fps_fast8_kernel<<<NSEG, 1024, 0, stream>>>(d2m, fps_idx);
  } else {
    // fallback: distributed MALL-sync FPS (fp16-packed registers)
    hipMemsetAsync(cand, 0, 512, stream);
    fps_kernel<<<NSEG * FPS_WGS_PER_SEG, FPS_THREADS, 0, stream>>>(
        xyz, feat, cand, fps_idx);
  }
  gather_kernel<<<M_TOTAL / 256, 256, 0, stream>>>(xyz, vel, fps_idx, out);
  knn_kernel<<<M_TOTAL / 16, 256, 0, stream>>>(xyz, out, knn);
  gemm_kernel<<<M_TOTAL, 128, 0, stream>>>(feat, W, knn, out);
}

// Round 13
// 2090.552 us; speedup vs baseline: 3.1603x; 1.2116x over previous
//
#include <hip/hip_runtime.h>
#include <hip/hip_fp16.h>

typedef unsigned long long u64;

#define SEG_N     8192
#define NSEG      2
#define M_PER_SEG 2048
#define M_TOTAL   4096
#define CFEAT     64
#define COUT      128
#define NSAMPLE   16

#define FPS_WGS_PER_SEG 16
#define FPS_THREADS     512
#define FPS_WAVES       8
#define SLOT_STRIDE     16    // u64s per (parity,seg) row = 128B line

// d_out layout (floats): new_xyz | new_feat | new_offset | new_vel
#define OUT_XYZ   0
#define OUT_FEAT  12288      // 4096*3
#define OUT_OFF   536576     // + 4096*128
#define OUT_VEL   536578     // + 2

// d_ws layout (bytes)
#define WS_CAND 0            // u64 cand[2][2][16]  (fallback sync slots)
#define WS_FPS  512          // int fps_idx[2][2048]
#define WS_KNN  16896        // int knn[4096][16]
#define WS_SQ   (1<<19)      // float sq[16384]
#define WS_D2   (1<<20)      // u8 D2 matrix region (2 x 67MB)
#define D2_SEG8 ((size_t)SEG_N * SEG_N)       // 67 MB per segment (u8)

#define AG  __HIP_MEMORY_SCOPE_AGENT
#define RLX __ATOMIC_RELAXED

#define REP16(M) M(0) M(1) M(2) M(3) M(4) M(5) M(6) M(7) \
                 M(8) M(9) M(10) M(11) M(12) M(13) M(14) M(15)
#define REP16_EO(E,O) E(0) O(1) E(2) O(3) E(4) O(5) E(6) O(7) \
                      E(8) O(9) E(10) O(11) E(12) O(13) E(14) O(15)

__device__ __forceinline__ unsigned pk2(float a, float b) {
  __half2 h = __floats2half2_rn(a, b);
  unsigned u; __builtin_memcpy(&u, &h, 4); return u;
}
__device__ __forceinline__ float2 up2(unsigned u) {
  __half2 h; __builtin_memcpy(&h, &u, 4);
  return __half22float2(h);
}

// DPP max step: masked-off / out-of-bounds lanes contribute 0 (identity for
// unsigned max). VALU op, ~6-8 cyc dependent latency vs ~120 for ds_bpermute.
template<int CTRL, int RM>
__device__ __forceinline__ unsigned dppmax(unsigned c) {
  int t = __builtin_amdgcn_update_dpp(0, (int)c, CTRL, RM, 0xF, true);
  unsigned u = (unsigned)t;
  return c > u ? c : u;
}

// ===========================================================================
// FAST PATH: u8 d^2 matrix (scale 1.0, clamp 255), 67MB/segment, both
// segments resident + largely L3-cached. FPS: one WG per segment, zero
// cross-WG sync, DPP-based reductions (no ds_bpermute on the critical path).
// ===========================================================================

__global__ __launch_bounds__(256)
void norm_kernel(const float* __restrict__ xyz, const float* __restrict__ feat,
                 float* __restrict__ sq)
{
  int i = blockIdx.x * 256 + threadIdx.x;
  if (i >= NSEG * SEG_N) return;
  float a0 = xyz[(size_t)i*3+0], a1 = xyz[(size_t)i*3+1], a2 = xyz[(size_t)i*3+2];
  float acc = a0*a0 + a1*a1 + a2*a2;
  const float4* fr = (const float4*)(feat + (size_t)i * CFEAT);
  #pragma unroll
  for (int k = 0; k < 16; ++k) {
    float4 v = fr[k];
    acc += v.x*v.x + v.y*v.y + v.z*v.z + v.w*v.w;
  }
  sq[i] = acc;
}

// rank-67 GEMM -> u8 d^2 tile (128q x 64p per block), both segments.
__global__ __launch_bounds__(256)
void gram8_kernel(const float* __restrict__ xyz, const float* __restrict__ feat,
                  const float* __restrict__ sq, unsigned char* __restrict__ d2m)
{
  __shared__ float Aq[68][132];
  __shared__ float Ap[68][68];

  const int b   = blockIdx.x;
  const int s   = b >> 13;              // 8192 blocks per segment
  const int rem = b & 8191;
  const int tq  = rem >> 7;             // 0..63  (q tiles of 128)
  const int tp  = rem & 127;            // 0..127 (p tiles of 64)
  const int q0  = tq * 128, p0 = tp * 64;
  const int tid = threadIdx.x;
  unsigned char* d2seg = d2m + (size_t)s * D2_SEG8;

  for (int e = tid; e < 128 * 64; e += 256) {
    int r = e >> 6, c = e & 63;
    Aq[3 + c][r] = feat[(size_t)(s * SEG_N + q0 + r) * CFEAT + c];
  }
  for (int e = tid; e < 128 * 3; e += 256) {
    int r = e / 3, d = e - r * 3;
    Aq[d][r] = xyz[(size_t)(s * SEG_N + q0 + r) * 3 + d];
  }
  for (int e = tid; e < 64 * 64; e += 256) {
    int r = e >> 6, c = e & 63;
    Ap[3 + c][r] = feat[(size_t)(s * SEG_N + p0 + r) * CFEAT + c];
  }
  for (int e = tid; e < 64 * 3; e += 256) {
    int r = e / 3, d = e - r * 3;
    Ap[d][r] = xyz[(size_t)(s * SEG_N + p0 + r) * 3 + d];
  }
  __syncthreads();

  const int ty = tid >> 4, tx = tid & 15;   // 8q x 4p per thread
  float acc[8][4];
  #pragma unroll
  for (int i = 0; i < 8; ++i)
    #pragma unroll
    for (int j = 0; j < 4; ++j) acc[i][j] = 0.f;

  for (int k = 0; k < 67; ++k) {
    const float* aq = &Aq[k][ty * 8];
    const float* bp = &Ap[k][tx * 4];
    float a[8], bb[4];
    #pragma unroll
    for (int i = 0; i < 8; ++i) a[i] = aq[i];
    #pragma unroll
    for (int j = 0; j < 4; ++j) bb[j] = bp[j];
    #pragma unroll
    for (int i = 0; i < 8; ++i)
      #pragma unroll
      for (int j = 0; j < 4; ++j) acc[i][j] += a[i] * bb[j];
  }

  float sp[4];
  #pragma unroll
  for (int j = 0; j < 4; ++j) sp[j] = sq[s * SEG_N + p0 + tx * 4 + j];

  #pragma unroll
  for (int i = 0; i < 8; ++i) {
    int qrow = q0 + ty * 8 + i;
    float sqq = sq[s * SEG_N + qrow];
    unsigned o[4];
    #pragma unroll
    for (int j = 0; j < 4; ++j) {
      float d2 = sqq + sp[j] - 2.f * acc[i][j];
      d2 = fmaxf(d2, 0.f);
      o[j] = __float2uint_rn(fminf(d2, 255.f));
    }
    unsigned pkd = o[0] | (o[1] << 8) | (o[2] << 16) | (o[3] << 24);
    *(unsigned*)&d2seg[((size_t)qrow << 13) + (p0 + tx * 4)] = pkd;
  }
}

// FPS from the u8 matrix: one WG per segment (grid=2), 1024 threads x 8
// points. Per step: one 8B row-slice load (saddr, q uniform via readlane),
// 8 u8 mins, packed u32 candidates (dist<<13 | 8191-idx), DPP wave-max
// (row_shr 1/2/4/8 + bcast15/31 -> lane63, readlane), parity-double-buffered
// 16-slot LDS funnel, ONE barrier, DPP 16-slot max + readlane -> scalar q.
__global__ __launch_bounds__(1024)
void fps_fast8_kernel(const unsigned char* __restrict__ d2m,
                      int* __restrict__ fps_idx)
{
  __shared__ unsigned wslot[2][16];

  const int tid  = threadIdx.x;
  const int lane = tid & 63;
  const int wv   = tid >> 6;
  const int s    = blockIdx.x;
  const int p0   = tid * 8;
  const unsigned idx0 = 8191 - p0;          // inv-index of my point k=0
  const unsigned char* base_s = d2m + (size_t)s * D2_SEG8;

  unsigned D0=255u,D1=255u,D2v=255u,D3=255u,D4=255u,D5=255u,D6=255u,D7=255u;

  if (tid == 0) fps_idx[s * M_PER_SEG] = 0;
  int q = 0;

  for (int t = 1; t < M_PER_SEG; ++t) {
    uint2 w = *(const uint2*)(base_s + ((size_t)q << 13) + p0);
    unsigned a = w.x, b = w.y;
    D0 = min(D0,  a        & 255u);
    D1 = min(D1, (a >>  8) & 255u);
    D2v= min(D2v,(a >> 16) & 255u);
    D3 = min(D3,  a >> 24);
    D4 = min(D4,  b        & 255u);
    D5 = min(D5, (b >>  8) & 255u);
    D6 = min(D6, (b >> 16) & 255u);
    D7 = min(D7,  b >> 24);

    // packed candidates: dist<<13 | inv-idx  (ties -> lowest point index)
    unsigned c = (D0 << 13) | idx0;
    c = max(c, (D1 << 13) | (idx0 - 1u));
    c = max(c, (D2v<< 13) | (idx0 - 2u));
    c = max(c, (D3 << 13) | (idx0 - 3u));
    c = max(c, (D4 << 13) | (idx0 - 4u));
    c = max(c, (D5 << 13) | (idx0 - 5u));
    c = max(c, (D6 << 13) | (idx0 - 6u));
    c = max(c, (D7 << 13) | (idx0 - 7u));

    // 64-lane DPP max reduce -> lane 63
    c = dppmax<0x111, 0xF>(c);   // row_shr:1
    c = dppmax<0x112, 0xF>(c);   // row_shr:2
    c = dppmax<0x114, 0xF>(c);   // row_shr:4
    c = dppmax<0x118, 0xF>(c);   // row_shr:8
    c = dppmax<0x142, 0xA>(c);   // row_bcast:15 (rows 1,3)
    c = dppmax<0x143, 0xC>(c);   // row_bcast:31 (rows 2,3)
    unsigned wmax = (unsigned)__builtin_amdgcn_readlane((int)c, 63);

    if (lane == 0) wslot[t & 1][wv] = wmax;
    __syncthreads();                       // single barrier per step

    unsigned v = wslot[t & 1][lane & 15];
    v = dppmax<0x111, 0xF>(v);
    v = dppmax<0x112, 0xF>(v);
    v = dppmax<0x114, 0xF>(v);
    v = dppmax<0x118, 0xF>(v);             // lane15 of each row = global max
    unsigned gmax = (unsigned)__builtin_amdgcn_readlane((int)v, 15);
    q = 8191 - (int)(gmax & 0x1FFFu);      // uniform (SGPR) -> saddr row load
    if (tid == 0) fps_idx[s * M_PER_SEG + t] = q;
  }
}

// ===========================================================================
// FALLBACK: distributed MALL-sync FPS, fp16-packed named registers.
// ===========================================================================
__global__ __attribute__((amdgpu_waves_per_eu(2, 2)))
__launch_bounds__(FPS_THREADS)
void fps_kernel(const float* __restrict__ xyz, const float* __restrict__ feat,
                u64* __restrict__ cand, int* __restrict__ fps_idx)
{
#pragma clang fp contract(off)
  __shared__ u64 wslot[FPS_WAVES];
  __shared__ int qidx_sh;

  const int tid  = threadIdx.x;
  const int lane = tid & 63;
  const int wv   = tid >> 6;
  const int s    = blockIdx.x >> 4;
  const int wg   = blockIdx.x & 15;
  const int pl   = wg * FPS_THREADS + tid;
  const size_t gr = (size_t)(s * SEG_N + pl);

  float px, py, pz;
#define DECLP(k) uint2 pp##k;
  REP16(DECLP)
  px = xyz[gr*3+0]; py = xyz[gr*3+1]; pz = xyz[gr*3+2];
  {
    const float4* fr = (const float4*)(feat + gr * CFEAT);
#define LOADP(k) { float4 v = fr[k]; pp##k.x = pk2(v.x, v.y); pp##k.y = pk2(v.z, v.w); }
    REP16(LOADP)
  }

  float qx, qy, qz;
#define DECLQ(k) float4 qf##k;
  REP16(DECLQ)
#define LOADQ1(k) qf##k = frq[k];
#define LOAD_Q(qb) { \
    qx = xyz[(qb)*3+0]; qy = xyz[(qb)*3+1]; qz = xyz[(qb)*3+2]; \
    const float4* frq = (const float4*)(feat + (qb) * CFEAT); \
    REP16(LOADQ1) }

  LOAD_Q((size_t)(s * SEG_N))
  if (tid == 0 && wg == 0) fps_idx[s * M_PER_SEG] = 0;

  float D = 1e10f;

  for (int t = 1; t < M_PER_SEG; ++t) {
    float r0=0.f, r1=0.f, r2=0.f, r3=0.f, r4=0.f, r5=0.f, r6=0.f, r7=0.f;
    {
      float tt;
      tt = px - qx; r0 += tt*tt;
      tt = py - qy; r1 += tt*tt;
      tt = pz - qz; r2 += tt*tt;
    }
#define DE(k) { float2 ab = up2(pp##k.x), cd = up2(pp##k.y); \
                float t0 = ab.x - qf##k.x; r3 += t0*t0; \
                float t1 = ab.y - qf##k.y; r4 += t1*t1; \
                float t2 = cd.x - qf##k.z; r5 += t2*t2; \
                float t3 = cd.y - qf##k.w; r6 += t3*t3; }
#define DO(k) { float2 ab = up2(pp##k.x), cd = up2(pp##k.y); \
                float t0 = ab.x - qf##k.x; r7 += t0*t0; \
                float t1 = ab.y - qf##k.y; r0 += t1*t1; \
                float t2 = cd.x - qf##k.z; r1 += t2*t2; \
                float t3 = cd.y - qf##k.w; r2 += t3*t3; }
    REP16_EO(DE, DO)
    float a = ((r0+r1)+(r2+r3)) + ((r4+r5)+(r6+r7));
    D = fminf(D, a);

    float bd = D; int bi = pl;
    #pragma unroll
    for (int off = 32; off >= 1; off >>= 1) {
      float od = __shfl_xor(bd, off);
      int   oi = __shfl_xor(bi, off);
      if (od > bd || (od == bd && oi < bi)) { bd = od; bi = oi; }
    }
    if (lane == 0)
      wslot[wv] = ((u64)__float_as_uint(bd) << 13) | (u64)(unsigned)(8191 - bi);
    __syncthreads();

    if (wv == 0) {
      u64 w = (lane < FPS_WAVES) ? wslot[lane] : 0ULL;
      #pragma unroll
      for (int off = 4; off >= 1; off >>= 1) {
        u64 o = __shfl_xor(w, off, 8);
        if (o > w) w = o;
      }
      u64* base = &cand[(((unsigned)t & 1u) * NSEG + s) * SLOT_STRIDE];
      if (lane == 0)
        __hip_atomic_store(&base[wg], ((u64)(unsigned)t << 45) | w, RLX, AG);

      u64 v = 0;
      if (lane < FPS_WGS_PER_SEG) {
        v = __hip_atomic_load(&base[lane], RLX, AG);
        while ((unsigned)(v >> 45) != (unsigned)t) {
          __builtin_amdgcn_s_sleep(1);
          v = __hip_atomic_load(&base[lane], RLX, AG);
        }
      }
      #pragma unroll
      for (int off = 8; off >= 1; off >>= 1) {
        u64 o = __shfl_xor(v, off, 16);
        if (o > v) v = o;
      }
      int qi = 8191 - (int)(v & 0x1FFFu);
      if (lane == 0) {
        qidx_sh = qi;
        if (wg == 0) fps_idx[s * M_PER_SEG + t] = qi;
      }
    }
    __syncthreads();

    LOAD_Q((size_t)(s * SEG_N + qidx_sh))
  }
}

// ---------------------------------------------------------------------------
__global__ void gather_kernel(const float* __restrict__ xyz, const float* __restrict__ vel,
                              const int* __restrict__ fps_idx, float* __restrict__ out)
{
  int i = blockIdx.x * 256 + threadIdx.x;
  if (i >= M_TOTAL) return;
  int s = i >> 11, r = i & 2047;
  int g = s * SEG_N + (fps_idx[s * M_PER_SEG + r] & 8191);
  out[OUT_XYZ + i*3 + 0] = xyz[(size_t)g*3 + 0];
  out[OUT_XYZ + i*3 + 1] = xyz[(size_t)g*3 + 1];
  out[OUT_XYZ + i*3 + 2] = xyz[(size_t)g*3 + 2];
  out[OUT_VEL + i*3 + 0] = vel[(size_t)g*3 + 0];
  out[OUT_VEL + i*3 + 1] = vel[(size_t)g*3 + 1];
  out[OUT_VEL + i*3 + 2] = vel[(size_t)g*3 + 2];
  if (i == 0) { out[OUT_OFF] = 2048.0f; out[OUT_OFF + 1] = 4096.0f; }
}

// ---------------------------------------------------------------------------
#define KNN_TILE 1024
__global__ __launch_bounds__(256)
void knn_kernel(const float* __restrict__ xyz, const float* __restrict__ out,
                int* __restrict__ knn)
{
  __shared__ float px[KNN_TILE], py[KNN_TILE], pz[KNN_TILE];
  __shared__ float ldK[16][16][16];
  __shared__ float Tq[16];
  __shared__ float dbuf[16][24];
  __shared__ int   cbuf[16][24];
  __shared__ int   cnt[16];

  const int tid = threadIdx.x;
  const int ql = tid >> 4, j = tid & 15;
  const int qg = blockIdx.x * 16 + ql;
  const int s  = qg >> 11;
  const float qx = out[OUT_XYZ + qg*3 + 0];
  const float qy = out[OUT_XYZ + qg*3 + 1];
  const float qz = out[OUT_XYZ + qg*3 + 2];
  const float sq = qx*qx + qy*qy + qz*qz;

  float K[16];
  #pragma unroll
  for (int r = 0; r < 16; ++r) K[r] = 3.4e38f;

  for (int tile = 0; tile < SEG_N / KNN_TILE; ++tile) {
    __syncthreads();
    for (int u = tid; u < KNN_TILE; u += 256) {
      size_t g = (size_t)(s * SEG_N + tile * KNN_TILE + u);
      px[u] = xyz[g*3+0]; py[u] = xyz[g*3+1]; pz[u] = xyz[g*3+2];
    }
    __syncthreads();
    #pragma unroll 4
    for (int i = 0; i < KNN_TILE / 16; ++i) {
      int c = i * 16 + j;
      float x = px[c], y = py[c], z = pz[c];
      float sp  = x*x + y*y + z*z;
      float dot = qx*x + qy*y + qz*z;
      float d2  = (sq + sp) - 2.0f * dot;
      #pragma unroll
      for (int r = 15; r >= 1; --r)
        K[r] = fminf(fmaxf(d2, K[r-1]), K[r]);
      K[0] = fminf(K[0], d2);
    }
  }
  #pragma unroll
  for (int r = 0; r < 16; ++r) ldK[ql][j][r] = K[r];
  __syncthreads();

  {
    int head = 0;
    float T = 3.4e38f;
    for (int r = 0; r < 16; ++r) {
      float val = (head < 16) ? ldK[ql][j][head] : 3.4e38f;
      float mv = val; int ml = j;
      #pragma unroll
      for (int off = 8; off >= 1; off >>= 1) {
        float ov = __shfl_xor(mv, off, 16);
        int   ol = __shfl_xor(ml, off, 16);
        if (ov < mv || (ov == mv && ol < ml)) { mv = ov; ml = ol; }
      }
      if (j == ml) head++;
      T = mv;
    }
    if (j == 0) { Tq[ql] = T; cnt[ql] = 0; }
  }
  __syncthreads();
  const float T  = Tq[ql];
  const float Tm = T + fabsf(T) * 1e-6f + 1e-30f;

  for (int tile = 0; tile < SEG_N / KNN_TILE; ++tile) {
    __syncthreads();
    for (int u = tid; u < KNN_TILE; u += 256) {
      size_t g = (size_t)(s * SEG_N + tile * KNN_TILE + u);
      px[u] = xyz[g*3+0]; py[u] = xyz[g*3+1]; pz[u] = xyz[g*3+2];
    }
    __syncthreads();
    for (int i = 0; i < KNN_TILE / 16; ++i) {
      int c = i * 16 + j;
      float x = px[c], y = py[c], z = pz[c];
      float sp  = x*x + y*y + z*z;
      float dot = qx*x + qy*y + qz*z;
      float d2  = (sq + sp) - 2.0f * dot;
      if (d2 <= Tm) {
        int pos = atomicAdd(&cnt[ql], 1);
        if (pos < 24) { dbuf[ql][pos] = d2; cbuf[ql][pos] = tile * KNN_TILE + c; }
      }
    }
  }
  __syncthreads();

  if (j == 0) {
    int n = cnt[ql]; if (n > 24) n = 24;
    for (int r = 0; r < NSAMPLE; ++r) {
      float bv = 3.4e38f; int bc = 0, bp = -1;
      for (int e = 0; e < n; ++e) {
        float dv = dbuf[ql][e]; int cc = cbuf[ql][e];
        if (dv < bv || (dv == bv && cc < bc)) { bv = dv; bc = cc; bp = e; }
      }
      if (bp >= 0) dbuf[ql][bp] = 3.4e38f;
      knn[qg * NSAMPLE + r] = bc;
    }
  }
}

// ---------------------------------------------------------------------------
__global__ __launch_bounds__(128)
void gemm_kernel(const float* __restrict__ feat, const float* __restrict__ W,
                 const int* __restrict__ knn, float* __restrict__ out)
{
  __shared__ __align__(16) float f[NSAMPLE][CFEAT];
  __shared__ int kid[NSAMPLE];
  const int tid = threadIdx.x;
  const int q = blockIdx.x;
  const int s = q >> 11;
  if (tid < NSAMPLE) kid[tid] = knn[q * NSAMPLE + tid] & 8191;
  __syncthreads();
  for (int e = tid; e < NSAMPLE * CFEAT; e += 128) {
    int k = e >> 6, c = e & 63;
    f[k][c] = feat[(size_t)(s * SEG_N + kid[k]) * CFEAT + c];
  }
  float4 w[16];
  const float4* Wrow = (const float4*)(W + (size_t)tid * CFEAT);
  #pragma unroll
  for (int c4 = 0; c4 < 16; ++c4) w[c4] = Wrow[c4];
  __syncthreads();

  float m = -3.4e38f;
  #pragma unroll
  for (int k = 0; k < NSAMPLE; ++k) {
    float acc = 0.f;
    const float4* frow = (const float4*)&f[k][0];
    #pragma unroll
    for (int c4 = 0; c4 < 16; ++c4) {
      float4 fv = frow[c4];
      acc += fv.x * w[c4].x + fv.y * w[c4].y + fv.z * w[c4].z + fv.w * w[c4].w;
    }
    m = fmaxf(m, acc);
  }
  out[OUT_FEAT + (size_t)q * COUT + tid] = fmaxf(m, 0.f);
}

// ---------------------------------------------------------------------------
extern "C" void kernel_launch(void* const* d_in, const int* in_sizes, int n_in,
                              void* d_out, int out_size, void* d_ws, size_t ws_size,
                              hipStream_t stream)
{
  const float* xyz  = (const float*)d_in[0];
  const float* feat = (const float*)d_in[1];
  // d_in[2] = offset (segment sizes fixed by the problem)
  const float* vel  = (const float*)d_in[3];
  const float* W    = (const float*)d_in[4];
  float* out = (float*)d_out;
  char*  ws  = (char*)d_ws;
  u64* cand    = (u64*)(ws + WS_CAND);
  int* fps_idx = (int*)(ws + WS_FPS);
  int* knn     = (int*)(ws + WS_KNN);

  if (ws_size >= (size_t)WS_D2 + NSEG * D2_SEG8) {
    // u8 matrix path: both segments resident + L3-cached, FPS in parallel
    float* sq = (float*)(ws + WS_SQ);
    unsigned char* d2m = (unsigned char*)(ws + WS_D2);
    norm_kernel<<<(NSEG * SEG_N) / 256, 256, 0, stream>>>(xyz, feat, sq);
    gram8_kernel<<<NSEG * (SEG_N / 128) * (SEG_N / 64), 256, 0, stream>>>(
        xyz, feat, sq, d2m);
    fps_fast8_kernel<<<NSEG, 1024, 0, stream>>>(d2m, fps_idx);
  } else {
    // fallback: distributed MALL-sync FPS (fp16-packed registers)
    hipMemsetAsync(cand, 0, 512, stream);
    fps_kernel<<<NSEG * FPS_WGS_PER_SEG, FPS_THREADS, 0, stream>>>(
        xyz, feat, cand, fps_idx);
  }
  gather_kernel<<<M_TOTAL / 256, 256, 0, stream>>>(xyz, vel, fps_idx, out);
  knn_kernel<<<M_TOTAL / 16, 256, 0, stream>>>(xyz, out, knn);
  gemm_kernel<<<M_TOTAL, 128, 0, stream>>>(feat, W, knn, out);
}